// Round 11
// baseline (489.891 us; speedup 1.0000x reference)
//
#include <hip/hip_runtime.h>
#include <hip/hip_bf16.h>

// AutoInt+MLP fused forward, MI355X gfx950.  Round 11:
//  MERGED dispatch: attn (round-10 arena kernel, proven) + dnn (round-7, proven)
//  run as block roles of ONE kernel (8704 blocks; blockIdx%17==16 -> dnn) so
//  dnn's L2/MFMA work fills attn's latency stalls instead of running serially.
//  dnn writes its relu'd logit to ws; a tiny combine kernel does sigmoid(att+dnn).
//  HARD RULE (r5/r8/r9/r6 evidence): never use the 2-arg __launch_bounds__ on
//  this stack — (256,N) corrupts results / occupancy. Plain (256) only.

#define NF     39
#define EMB    64
#define NLAYER 3
#define VOCAB  1000
#define FLAT   2496
#define H1     512
#define H2     256

typedef __attribute__((ext_vector_type(8))) short  short8;
typedef __attribute__((ext_vector_type(4))) float  floatx4;

__device__ __forceinline__ short8 ld8s(const unsigned short* p) {
    return *(const short8*)p;
}
__device__ __forceinline__ float b2f(unsigned short h) {
    union { unsigned u; float f; } x; x.u = ((unsigned)h) << 16; return x.f;
}
__device__ __forceinline__ unsigned short f2b(float f) {
    union { float f; unsigned u; } x; x.f = f;
    unsigned u = x.u;
    return (unsigned short)((u + 0x7fffu + ((u >> 16) & 1u)) >> 16);
}
// 2 floats -> packed bf16x2 in ONE VALU op (gfx950 hw cvt, RNE)
__device__ __forceinline__ unsigned cvt_pk(float a, float b) {
#if defined(__gfx950__)
    unsigned r;
    asm("v_cvt_pk_bf16_f32 %0, %1, %2" : "=v"(r) : "v"(a), "v"(b));
    return r;
#else
    return (unsigned)f2b(a) | ((unsigned)f2b(b) << 16);
#endif
}

// ------- prep: attention weights f32 [L][64(k)][64(o)] -> bf16 [L][o][k] --------------
__global__ void attw_t(const float* __restrict__ WQ, const float* __restrict__ WK,
                       const float* __restrict__ WV, const float* __restrict__ WR,
                       unsigned short* __restrict__ wqt, unsigned short* __restrict__ wkt,
                       unsigned short* __restrict__ wvt, unsigned short* __restrict__ wrt)
{
    int idx = blockIdx.x * 256 + threadIdx.x;       // 4*3*4096 = 49152
    if (idx >= 4 * 3 * 4096) return;
    int mat = idx / 12288;
    int rem = idx % 12288;
    int l   = rem / 4096;
    int ok  = rem % 4096;
    int o = ok >> 6, k = ok & 63;
    const float*    src = (mat == 0) ? WQ : (mat == 1) ? WK : (mat == 2) ? WV : WR;
    unsigned short* dst = (mat == 0) ? wqt : (mat == 1) ? wkt : (mat == 2) ? wvt : wrt;
    dst[l * 4096 + o * 64 + k] = f2b(src[l * 4096 + k * 64 + o]);
}

// ------- prep: W1 f32 [2496][512] -> bf16 fragment-linear w1p --------------------------
__global__ void w1pack(const float* __restrict__ W1, unsigned short* __restrict__ w1p)
{
    int t = blockIdx.x * 256 + threadIdx.x;        // 624*256 = 159744 = 2496*64
    int lane = t & 63, grp = t >> 6;               // grp 0..2495
    int ot = grp / 78, kk = grp % 78;
    int q = lane >> 4, n = ot * 16 + (lane & 15);
    int kb = kk * 32 + q * 8;
    unsigned short* dst = w1p + grp * 512 + lane * 8;
    #pragma unroll
    for (int j = 0; j < 8; ++j)
        dst[j] = f2b(W1[(kb + j) * 512 + n]);
}

// ------- prep: W2 f32 [512][256] -> bf16 fragment-linear w2p ---------------------------
__global__ void w2pack(const float* __restrict__ W2, unsigned short* __restrict__ w2p)
{
    int t = blockIdx.x * 256 + threadIdx.x;        // 64*256 = 16384 = 256*64
    int lane = t & 63, grp = t >> 6;               // grp 0..255
    int ot = grp / 16, kk = grp % 16;
    int q = lane >> 4, n = ot * 16 + (lane & 15);
    int kb = kk * 32 + q * 8;
    unsigned short* dst = w2p + grp * 512 + lane * 8;
    #pragma unroll
    for (int j = 0; j < 8; ++j)
        dst[j] = f2b(W2[(kb + j) * 256 + n]);
}

// ------- merged attn+dnn kernel -------------------------------------------------------
// 8704 blocks x 256 thr. blockIdx%17==16 -> dnn role (512 blocks, interleaved);
// else attn role (8192 blocks). Shared LDS pool 52224 B -> 3 blocks/CU.
//  attn: round-10 arena layout (xs 13824 + arena 4x9472 + red 16 = 51728 B).
//  dnn : round-7 layout (ea dbuf 9216 + h1s 33280 = 42496 B).
__global__ void __launch_bounds__(256) fused_kernel(
    const int* __restrict__ X,
    const float* __restrict__ embf,
    const unsigned short* __restrict__ wqt,
    const unsigned short* __restrict__ wkt,
    const unsigned short* __restrict__ wvt,
    const unsigned short* __restrict__ wrt,
    const float* __restrict__ wlinf,
    const unsigned short* __restrict__ w1p,
    const float* __restrict__ b1v,
    const unsigned short* __restrict__ w2p,
    const float* __restrict__ b2v,
    const float* __restrict__ w3v,
    const float* __restrict__ b3v,
    float* __restrict__ att_out,
    float* __restrict__ dnn_out)
{
    __shared__ unsigned short smem[26112];        // 52224 B pool, carved per role

    const int tid  = threadIdx.x;
    const int wid  = tid >> 6;
    const int lane = tid & 63;
    const int quad = lane >> 4;
    const int l16  = lane & 15;
    const unsigned b = blockIdx.x;

    if (b % 17 != 16) {
        // =========================== ATTN ROLE (round-10 verbatim) ====================
        const int ablk = (int)(b - (b + 1) / 17);     // 0..8191
        const int sl   = wid >> 1;          // sample-in-block
        const int h    = wid & 1;           // head
        const int samp = ablk * 2 + sl;

        unsigned short* xss = smem + sl * 3456;            // xs[2][48*72]
        unsigned short* qs  = smem + 6912 + wid * 4736;    // arena[4][4736]
        unsigned short* ks  = qs + 1920;
        unsigned short* Ps  = qs;           // alias (qs/ks dead after S^T)
        unsigned short* vt  = qs + 3456;    // 32 x 40 (one 32-token K-half)
        float* red = (float*)(smem + 25856);

        // ---- embedding gather: wave fills its sample's cols h*32..h*32+31 -------------
        {
            const int tq = lane >> 4;            // 0..3
            const int cp = (lane & 15) * 2;      // 0,2,..,30
            const int col = h * 32 + cp;
            const int* xrow = X + samp * NF;
            #pragma unroll
            for (int t0 = 0; t0 < 48; t0 += 4) {
                int t = t0 + tq;
                unsigned pk = 0;
                if (t < NF) {
                    int row = xrow[t] + t * VOCAB;
                    const float2 v = *(const float2*)&embf[row * EMB + col];
                    pk = cvt_pk(v.x, v.y);
                }
                *(unsigned*)&xss[t * 72 + col] = pk;   // rows 39..47 zeroed
            }
        }
        __syncthreads();

        for (int layer = 0; layer < NLAYER; ++layer) {
            const unsigned short* wq  = wqt + layer * 4096;
            const unsigned short* wk  = wkt + layer * 4096;
            const unsigned short* wvp = wvt + layer * 4096;
            const unsigned short* wr  = wrt + layer * 4096;

            // ---- Q,K projections -> qs, ks (row-major [tok][d]) -----------------------
            #pragma unroll
            for (int mat = 0; mat < 2; ++mat) {
                const unsigned short* wt = mat ? wk : wq;
                unsigned short* dst = mat ? ks : qs;
                #pragma unroll
                for (int mt = 0; mt < 3; ++mt) {
                    #pragma unroll
                    for (int nt = 0; nt < 2; ++nt) {
                        floatx4 c = {0.f, 0.f, 0.f, 0.f};
                        #pragma unroll
                        for (int kk = 0; kk < 2; ++kk) {
                            short8 a = ld8s(&xss[(mt * 16 + l16) * 72 + kk * 32 + quad * 8]);
                            short8 bb = ld8s(&wt[(h * 32 + nt * 16 + l16) * 64 + kk * 32 + quad * 8]);
                            c = __builtin_amdgcn_mfma_f32_16x16x32_bf16(a, bb, c, 0, 0, 0);
                        }
                        unsigned plo = cvt_pk(c[0], c[1]);
                        unsigned phi = cvt_pk(c[2], c[3]);
                        int base = (mt * 16 + quad * 4) * 40 + nt * 16 + l16;
                        dst[base]       = (unsigned short)plo;
                        dst[base + 40]  = (unsigned short)(plo >> 16);
                        dst[base + 80]  = (unsigned short)phi;
                        dst[base + 120] = (unsigned short)(phi >> 16);
                    }
                }
            }

            // ---- S^T = K @ Q^T ---------------------------------------------------------
            floatx4 ST[3][3];
            #pragma unroll
            for (int jt = 0; jt < 3; ++jt) {
                short8 a = ld8s(&ks[(jt * 16 + l16) * 40 + quad * 8]);
                #pragma unroll
                for (int it = 0; it < 3; ++it) {
                    short8 bb = ld8s(&qs[(it * 16 + l16) * 40 + quad * 8]);
                    floatx4 z = {0.f, 0.f, 0.f, 0.f};
                    ST[jt][it] = __builtin_amdgcn_mfma_f32_16x16x32_bf16(a, bb, z, 0, 0, 0);
                }
            }

            // ---- softmax over j; write P (A-layout) to Ps ------------------------------
            #pragma unroll
            for (int it = 0; it < 3; ++it) {
                float p[3][4];
                float sum = 0.f;
                #pragma unroll
                for (int jt = 0; jt < 3; ++jt)
                    #pragma unroll
                    for (int r = 0; r < 4; ++r) {
                        int j = jt * 16 + quad * 4 + r;
                        float e = (j < NF) ? __expf(ST[jt][it][r]) : 0.f;
                        p[jt][r] = e;
                        sum += e;
                    }
                sum += __shfl_xor(sum, 16, 64);
                sum += __shfl_xor(sum, 32, 64);
                float inv = 1.0f / sum;
                #pragma unroll
                for (int jt = 0; jt < 3; ++jt) {
                    uint2 w;
                    w.x = cvt_pk(p[jt][0] * inv, p[jt][1] * inv);
                    w.y = cvt_pk(p[jt][2] * inv, p[jt][3] * inv);
                    *(uint2*)&Ps[(it * 16 + l16) * 72 + jt * 16 + quad * 4] = w;
                }
                uint2 z2; z2.x = 0; z2.y = 0;                 // zero K-pad cols 48..63
                *(uint2*)&Ps[(it * 16 + l16) * 72 + 48 + quad * 4] = z2;
            }

            // ---- V projection: mt=0,1 -> vT (toks 0..31); mt=2 in regs -----------------
            unsigned sv[2][2];
            #pragma unroll
            for (int mt = 0; mt < 3; ++mt) {
                #pragma unroll
                for (int nt = 0; nt < 2; ++nt) {
                    floatx4 c = {0.f, 0.f, 0.f, 0.f};
                    #pragma unroll
                    for (int kk = 0; kk < 2; ++kk) {
                        short8 a = ld8s(&xss[(mt * 16 + l16) * 72 + kk * 32 + quad * 8]);
                        short8 bb = ld8s(&wvp[(h * 32 + nt * 16 + l16) * 64 + kk * 32 + quad * 8]);
                        c = __builtin_amdgcn_mfma_f32_16x16x32_bf16(a, bb, c, 0, 0, 0);
                    }
                    unsigned lo = cvt_pk(c[0], c[1]);
                    unsigned hi = cvt_pk(c[2], c[3]);
                    if (mt < 2) {
                        uint2 w; w.x = lo; w.y = hi;
                        *(uint2*)&vt[(nt * 16 + l16) * 40 + mt * 16 + quad * 4] = w;
                    } else {
                        sv[nt][0] = lo; sv[nt][1] = hi;
                    }
                }
            }

            // ---- R projection -> O init ------------------------------------------------
            floatx4 O[3][2];
            #pragma unroll
            for (int mt = 0; mt < 3; ++mt) {
                #pragma unroll
                for (int nt = 0; nt < 2; ++nt) {
                    floatx4 c = {0.f, 0.f, 0.f, 0.f};
                    #pragma unroll
                    for (int kk = 0; kk < 2; ++kk) {
                        short8 a = ld8s(&xss[(mt * 16 + l16) * 72 + kk * 32 + quad * 8]);
                        short8 bb = ld8s(&wr[(h * 32 + nt * 16 + l16) * 64 + kk * 32 + quad * 8]);
                        c = __builtin_amdgcn_mfma_f32_16x16x32_bf16(a, bb, c, 0, 0, 0);
                    }
                    O[mt][nt] = c;
                }
            }

            __syncthreads();   // all waves done reading xs

            // ---- PV kk=0: toks 0..31 ---------------------------------------------------
            {
                short8 a0 = ld8s(&Ps[(l16) * 72 + quad * 8]);
                short8 a1 = ld8s(&Ps[(16 + l16) * 72 + quad * 8]);
                short8 a2 = ld8s(&Ps[(32 + l16) * 72 + quad * 8]);
                #pragma unroll
                for (int nt = 0; nt < 2; ++nt) {
                    short8 bb = ld8s(&vt[(nt * 16 + l16) * 40 + quad * 8]);
                    O[0][nt] = __builtin_amdgcn_mfma_f32_16x16x32_bf16(a0, bb, O[0][nt], 0, 0, 0);
                    O[1][nt] = __builtin_amdgcn_mfma_f32_16x16x32_bf16(a1, bb, O[1][nt], 0, 0, 0);
                    O[2][nt] = __builtin_amdgcn_mfma_f32_16x16x32_bf16(a2, bb, O[2][nt], 0, 0, 0);
                }
            }
            // ---- refill vT with toks 32..63 (wave-private, program-ordered DS) ---------
            #pragma unroll
            for (int nt = 0; nt < 2; ++nt) {
                uint2 w; w.x = sv[nt][0]; w.y = sv[nt][1];
                *(uint2*)&vt[(nt * 16 + l16) * 40 + quad * 4] = w;
                uint2 z; z.x = 0; z.y = 0;
                *(uint2*)&vt[(nt * 16 + l16) * 40 + 16 + quad * 4] = z;
            }
            // ---- PV kk=1: toks 32..63 --------------------------------------------------
            {
                short8 a0 = ld8s(&Ps[(l16) * 72 + 32 + quad * 8]);
                short8 a1 = ld8s(&Ps[(16 + l16) * 72 + 32 + quad * 8]);
                short8 a2 = ld8s(&Ps[(32 + l16) * 72 + 32 + quad * 8]);
                #pragma unroll
                for (int nt = 0; nt < 2; ++nt) {
                    short8 bb = ld8s(&vt[(nt * 16 + l16) * 40 + quad * 8]);
                    O[0][nt] = __builtin_amdgcn_mfma_f32_16x16x32_bf16(a0, bb, O[0][nt], 0, 0, 0);
                    O[1][nt] = __builtin_amdgcn_mfma_f32_16x16x32_bf16(a1, bb, O[1][nt], 0, 0, 0);
                    O[2][nt] = __builtin_amdgcn_mfma_f32_16x16x32_bf16(a2, bb, O[2][nt], 0, 0, 0);
                }
            }

            // ---- next x = relu(O + xWr) ------------------------------------------------
            #pragma unroll
            for (int mt = 0; mt < 3; ++mt)
                #pragma unroll
                for (int nt = 0; nt < 2; ++nt) {
                    unsigned plo = cvt_pk(fmaxf(O[mt][nt][0], 0.f), fmaxf(O[mt][nt][1], 0.f));
                    unsigned phi = cvt_pk(fmaxf(O[mt][nt][2], 0.f), fmaxf(O[mt][nt][3], 0.f));
                    int base = (mt * 16 + quad * 4) * 72 + h * 32 + nt * 16 + l16;
                    xss[base]       = (unsigned short)plo;
                    xss[base + 72]  = (unsigned short)(plo >> 16);
                    xss[base + 144] = (unsigned short)phi;
                    xss[base + 216] = (unsigned short)(phi >> 16);
                }

            __syncthreads();
        }

        // ---- att logit: relu( att_flat . Wlin ) ---------------------------------------
        {
            float acc = 0.f;
            const int c = lane & 31, tp = lane >> 5;
            const int col = h * 32 + c;
            for (int t0 = 0; t0 < 40; t0 += 2) {
                int t = t0 + tp;
                if (t < NF)
                    acc += b2f(xss[t * 72 + col]) * wlinf[t * EMB + col];
            }
            #pragma unroll
            for (int off = 1; off < 64; off <<= 1)
                acc += __shfl_xor(acc, off, 64);
            if (lane == 0) red[wid] = acc;
            __syncthreads();
            if (tid < 2) {
                float v2 = red[tid * 2] + red[tid * 2 + 1];
                att_out[ablk * 2 + tid] = fmaxf(v2, 0.f);
            }
        }
    } else {
        // =========================== DNN ROLE (round-7 verbatim) ======================
        const int S0 = (int)(b / 17) * 32;            // dnn_idx 0..511

        unsigned short* ea0 = smem;                    // ea[2][32*72]
        unsigned short* ea1 = smem + 2304;
        unsigned short* h1s = smem + 4608;             // [32][520]; h2 aliases
        unsigned short* h2s = h1s;

        floatx4 C1[2][8];
        #pragma unroll
        for (int mt = 0; mt < 2; ++mt)
            #pragma unroll
            for (int nt = 0; nt < 8; ++nt)
                C1[mt][nt] = (floatx4){0.f, 0.f, 0.f, 0.f};

        const int gs = tid >> 3;        // 0..31 sample for staging
        const int gg = tid & 7;         // 8 floats each

        // prologue: stage field 0 into ea0
        {
            int row = X[(S0 + gs) * NF + 0];
            const float4* src = (const float4*)&embf[row * EMB + gg * 8];
            float4 v0 = src[0], v1 = src[1];
            uint4 u;
            u.x = cvt_pk(v0.x, v0.y); u.y = cvt_pk(v0.z, v0.w);
            u.z = cvt_pk(v1.x, v1.y); u.w = cvt_pk(v1.z, v1.w);
            *(uint4*)&ea0[gs * 72 + gg * 8] = u;
        }
        __syncthreads();

        // ---- phase 1: h1 = emb(32 x 2496) @ W1, dbuf, 1 sync/iter ----------------------
        for (int f = 0; f < NF; ++f) {
            unsigned short* enext = ((f + 1) & 1) ? ea1 : ea0;
            if (f < NF - 1) {
                int row = X[(S0 + gs) * NF + f + 1] + (f + 1) * VOCAB;
                const float4* src = (const float4*)&embf[row * EMB + gg * 8];
                float4 v0 = src[0], v1 = src[1];
                uint4 u;
                u.x = cvt_pk(v0.x, v0.y); u.y = cvt_pk(v0.z, v0.w);
                u.z = cvt_pk(v1.x, v1.y); u.w = cvt_pk(v1.z, v1.w);
                *(uint4*)&enext[gs * 72 + gg * 8] = u;
            }
            const unsigned short* eac = (f & 1) ? ea1 : ea0;
            short8 a[2][2];
            #pragma unroll
            for (int mt = 0; mt < 2; ++mt) {
                a[mt][0] = ld8s(&eac[(mt * 16 + l16) * 72 + quad * 8]);
                a[mt][1] = ld8s(&eac[(mt * 16 + l16) * 72 + 32 + quad * 8]);
            }
            #pragma unroll
            for (int nt = 0; nt < 8; ++nt) {
                const unsigned short* bp = w1p + (((wid * 8 + nt) * 78 + f * 2) * 64 + lane) * 8;
                short8 b0 = ld8s(bp);
                short8 b1 = ld8s(bp + 512);
                #pragma unroll
                for (int mt = 0; mt < 2; ++mt) {
                    C1[mt][nt] = __builtin_amdgcn_mfma_f32_16x16x32_bf16(a[mt][0], b0, C1[mt][nt], 0, 0, 0);
                    C1[mt][nt] = __builtin_amdgcn_mfma_f32_16x16x32_bf16(a[mt][1], b1, C1[mt][nt], 0, 0, 0);
                }
            }
            __syncthreads();   // waves may not drift >1 iter: protects both ea buffers
        }

        // bias + relu, write ALL of h1 to LDS (each wave owns 128 cols)
        #pragma unroll
        for (int nt = 0; nt < 8; ++nt) {
            float bb = b1v[wid * 128 + nt * 16 + l16];
            #pragma unroll
            for (int mt = 0; mt < 2; ++mt) {
                #pragma unroll
                for (int r = 0; r < 4; ++r) {
                    float v = fmaxf(C1[mt][nt][r] + bb, 0.f);
                    h1s[(mt * 16 + quad * 4 + r) * 520 + wid * 128 + nt * 16 + l16] = f2b(v);
                }
            }
        }
        __syncthreads();

        // ---- phase 2: h2 = h1(32 x 512) @ W2 ------------------------------------------
        floatx4 C2[2][4];
        #pragma unroll
        for (int mt = 0; mt < 2; ++mt)
            #pragma unroll
            for (int nt = 0; nt < 4; ++nt)
                C2[mt][nt] = (floatx4){0.f, 0.f, 0.f, 0.f};

        #pragma unroll 4
        for (int kk = 0; kk < 16; ++kk) {
            short8 a0 = ld8s(&h1s[(l16) * 520 + kk * 32 + quad * 8]);
            short8 a1 = ld8s(&h1s[(16 + l16) * 520 + kk * 32 + quad * 8]);
            #pragma unroll
            for (int nt = 0; nt < 4; ++nt) {
                short8 bb = ld8s(w2p + (((wid * 4 + nt) * 16 + kk) * 64 + lane) * 8);
                C2[0][nt] = __builtin_amdgcn_mfma_f32_16x16x32_bf16(a0, bb, C2[0][nt], 0, 0, 0);
                C2[1][nt] = __builtin_amdgcn_mfma_f32_16x16x32_bf16(a1, bb, C2[1][nt], 0, 0, 0);
            }
        }
        __syncthreads();    // h1 reads complete -> safe to alias h2s onto h1s

        #pragma unroll
        for (int nt = 0; nt < 4; ++nt) {
            float bb = b2v[wid * 64 + nt * 16 + l16];
            #pragma unroll
            for (int mt = 0; mt < 2; ++mt)
                #pragma unroll
                for (int r = 0; r < 4; ++r)
                    h2s[(mt * 16 + quad * 4 + r) * 264 + wid * 64 + nt * 16 + l16] =
                        f2b(fmaxf(C2[mt][nt][r] + bb, 0.f));
        }
        __syncthreads();

        // ---- phase 3: dnn logit = relu(h2 . W3 + b3) -> ws ----------------------------
        {
            int s = tid >> 3, part = tid & 7;     // 8 lanes per sample, 32 elems each
            float acc = 0.f;
            #pragma unroll 8
            for (int j = 0; j < 32; ++j) {
                int jj = part * 32 + j;
                acc += b2f(h2s[s * 264 + jj]) * w3v[jj];
            }
            acc += __shfl_xor(acc, 1, 64);
            acc += __shfl_xor(acc, 2, 64);
            acc += __shfl_xor(acc, 4, 64);
            if (part == 0)
                dnn_out[S0 + s] = fmaxf(acc + b3v[0], 0.f);
        }
    }
}

// ------- combine: out = sigmoid(att_logit + dnn_logit) --------------------------------
__global__ void combine_kernel(const float* __restrict__ att,
                               const float* __restrict__ dnnl,
                               float* __restrict__ out)
{
    int i = blockIdx.x * 256 + threadIdx.x;       // 64 blocks x 256 = 16384
    float v = att[i] + dnnl[i];
    out[i] = 1.f / (1.f + __expf(-v));
}

extern "C" void kernel_launch(void* const* d_in, const int* in_sizes, int n_in,
                              void* d_out, int out_size, void* d_ws, size_t ws_size,
                              hipStream_t stream)
{
    (void)in_sizes; (void)n_in; (void)out_size; (void)ws_size;

    const int*   X    = (const int*)d_in[0];
    const float* emb  = (const float*)d_in[1];
    const float* WQ   = (const float*)d_in[2];
    const float* WK   = (const float*)d_in[3];
    const float* WV   = (const float*)d_in[4];
    const float* WR   = (const float*)d_in[5];
    const float* W1   = (const float*)d_in[6];
    const float* b1   = (const float*)d_in[7];
    const float* W2   = (const float*)d_in[8];
    const float* b2   = (const float*)d_in[9];
    const float* W3   = (const float*)d_in[10];
    const float* b3   = (const float*)d_in[11];
    const float* Wlin = (const float*)d_in[12];

    char* ws = (char*)d_ws;
    float*          att_logit = (float*)ws;                          // 16384 f32 = 64KB
    float*          dnn_logit = (float*)(ws + 65536);                // 16384 f32 = 64KB
    unsigned short* wqt = (unsigned short*)(ws + 131072);            // 3*4096 shorts each
    unsigned short* wkt = wqt + 3 * 4096;
    unsigned short* wvt = wkt + 3 * 4096;
    unsigned short* wrt = wvt + 3 * 4096;
    unsigned short* w1p = wrt + 3 * 4096;                            // 2496*512 shorts
    unsigned short* w2p = w1p + 2496 * 512;                          // 256*512 shorts

    attw_t<<<192, 256, 0, stream>>>(WQ, WK, WV, WR, wqt, wkt, wvt, wrt);
    w1pack<<<624, 256, 0, stream>>>(W1, w1p);
    w2pack<<<64, 256, 0, stream>>>(W2, w2p);
    fused_kernel<<<8704, 256, 0, stream>>>(X, emb, wqt, wkt, wvt, wrt, Wlin,
                                           w1p, b1, w2p, b2, W3, b3,
                                           att_logit, dnn_logit);
    combine_kernel<<<64, 256, 0, stream>>>(att_logit, dnn_logit, (float*)d_out);
}